// Round 8
// baseline (183.424 us; speedup 1.0000x reference)
//
#include <hip/hip_runtime.h>
#include <math.h>

// ---------------- static problem structure (LMAX=4, taus=16) ----------------
#define NTRI 42
#define NCH  10752
#define B_SZ 256
#define PART_TOT 942080      // sum over l: 256*NT*16*NM (float2), ~7.5 MB

// triples sorted by (l,l1,l2); TTc = tile index within degree l
__constant__ int TLc[NTRI]  = {0,0,0,0,0, 1,1,1,1,1,1,1,1, 2,2,2,2,2,2,2,2,2,2, 3,3,3,3,3,3,3,3,3,3, 4,4,4,4,4,4,4,4,4};
__constant__ int TL1c[NTRI] = {0,1,2,3,4, 1,1,2,2,3,3,4,4, 1,2,2,2,3,3,3,4,4,4, 2,2,3,3,3,3,4,4,4,4, 2,3,3,3,4,4,4,4,4};
__constant__ int TL2c[NTRI] = {0,1,2,3,4, 0,1,1,2,2,3,3,4, 1,0,1,2,1,2,3,2,3,4, 1,2,0,1,2,3,1,2,3,4, 2,1,2,3,0,1,2,3,4};
__constant__ int TTc[NTRI]  = {0,1,2,3,4, 0,1,2,3,4,5,6,7, 0,1,2,3,4,5,6,7,8,9, 0,1,2,3,4,5,6,7,8,9, 0,1,2,3,4,5,6,7,8};

__constant__ int ROFFc[5] ={0,16,64,144,256};            // row offset in 400-row layout
__constant__ int KLc[5]   ={1280,2048,2560,2560,2304};   // t_FF[l]
__constant__ int GBASEc[5]={0,1280,3328,5888,8448};      // channel base
__constant__ int WOFFc[5] ={0,20480,53248,94208,135168}; // complex offset into W
__constant__ int NMc[5]   ={1,3,5,7,9};
__constant__ int NTc[5]   ={5,8,10,10,9};                // tiles per l
// partials: g_part[PBASE[l] + b*PSTR[l] + T*16*NM + o*NM + m]
__constant__ int PSTRc[5] ={80,384,800,1120,1296};
__constant__ int PBASEc[5]={0,20480,118784,323584,610304};

// ---------------- device globals ----------------
__device__ float  g_cgcD[NTRI][81];   // dense CG: slot = mi*n1 + p (host-filled)
__device__ float  g_vp[32*NCH];       // variance partials (non-atomic)
__device__ float  g_inv[NCH];
__device__ float2 g_part[PART_TOT];   // output partials (non-atomic)

// ------- kernel 1: variance pass — generic, LDS-staged, no atomics -----------
// grid (42, 32) = (triple, b-chunk of 8). 256 threads = channel (i,j).
__global__ void __launch_bounds__(256) k_var(const float2* __restrict__ Fs){
    __shared__ float2 As[144], Bs[144];
    __shared__ float  sC[81];
    const int tr=blockIdx.x, bc=blockIdx.y, t=threadIdx.x;
    const int l=TLc[tr], l1=TL1c[tr], l2=TL2c[tr], T=TTc[tr];
    const int nm=2*l+1, n1=2*l1+1, n2=2*l2+1, d=l1+l2-l;
    if(t<nm*n1) sC[t]=g_cgcD[tr][t];
    const int i=t>>4, j=t&15;
    float n2s=0.f;
    for(int b8=0;b8<8;b8++){
        const int b=bc*8+b8;
        __syncthreads();                       // previous iter's reads done
        if(t<16*n1) As[t]=Fs[b*400+ROFFc[l1]+t];
        if(t<16*n2) Bs[t]=Fs[b*400+ROFFc[l2]+t];
        __syncthreads();
        const float2* Ai=&As[i*n1];
        const float2* Bj=&Bs[j*n2];
        for(int mi=0;mi<nm;mi++){              // wave-uniform scalar loops
            int pLo = mi + l1 - l2 - l; if(pLo<0) pLo=0;
            int pHi = mi + l1 + l2 - l; if(pHi>2*l1) pHi=2*l1;
            float aR=0.f, aI=0.f;
            for(int p=pLo;p<=pHi;p++){
                const float c=sC[mi*n1+p];     // broadcast
                const float2 a=Ai[p], bv=Bj[mi-p+d];
                aR=fmaf(c, a.x*bv.x - a.y*bv.y, aR);
                aI=fmaf(c, a.x*bv.y + a.y*bv.x, aI);
            }
            n2s=fmaf(aR,aR,n2s); n2s=fmaf(aI,aI,n2s);
        }
    }
    g_vp[bc*NCH + GBASEc[l] + T*256 + t] = n2s;
}

// ------- kernel 2: reduce variance partials -> inv scale ----------------------
__global__ void __launch_bounds__(256) k_inv(){
    const int c = blockIdx.x*256 + threadIdx.x;     // NCH = 42*256
    float s=0.f;
    for(int bc=0;bc<32;bc++) s += g_vp[bc*NCH + c]; // coalesced per bc
    const int l = (c<1280)?0:(c<3328)?1:(c<5888)?2:(c<8448)?3:4;
    const float v = s/(256.0f*(float)(2*l+1));
    g_inv[c] = 1.0f/(sqrtf(v)+1e-5f);
}

// ------- kernel 3: fused CG + BN + matmul — generic, one tile per block -------
// grid (42, 256) = (triple, b). 256 threads.
__global__ void __launch_bounds__(256) k_mm(const float2* __restrict__ Fs,
                                            const float2* __restrict__ W2){
    __shared__ float2 As[144], Bs[144];
    __shared__ float  sC[81];
    __shared__ float2 sh[9*256];
    const int tr=blockIdx.x, b=blockIdx.y, t=threadIdx.x;
    const int l=TLc[tr], l1=TL1c[tr], l2=TL2c[tr], T=TTc[tr];
    const int nm=2*l+1, n1=2*l1+1, n2=2*l2+1, K=KLc[l], d=l1+l2-l;
    if(t<16*n1) As[t]=Fs[b*400+ROFFc[l1]+t];
    if(t<16*n2) Bs[t]=Fs[b*400+ROFFc[l2]+t];
    if(t<nm*n1) sC[t]=g_cgcD[tr][t];
    const float invv = g_inv[GBASEc[l]+T*256+t];
    __syncthreads();
    // phase A: per-channel CG, scale, stage to sh (no ff array)
    {
        const int i=t>>4, j=t&15;
        const float2* Ai=&As[i*n1];
        const float2* Bj=&Bs[j*n2];
        for(int mi=0;mi<nm;mi++){
            int pLo = mi + l1 - l2 - l; if(pLo<0) pLo=0;
            int pHi = mi + l1 + l2 - l; if(pHi>2*l1) pHi=2*l1;
            float aR=0.f, aI=0.f;
            for(int p=pLo;p<=pHi;p++){
                const float c=sC[mi*n1+p];
                const float2 a=Ai[p], bv=Bj[mi-p+d];
                aR=fmaf(c, a.x*bv.x - a.y*bv.y, aR);
                aI=fmaf(c, a.x*bv.y + a.y*bv.x, aI);
            }
            sh[mi*256+t]=make_float2(aR*invv, aI*invv);
        }
    }
    __syncthreads();
    // phase B: (o=t>>4, sub=t&15); w[16] preloaded, runtime m-loop, scalar acc
    const int o=t>>4, sub=t&15;
    const float2* __restrict__ Wrow = W2 + WOFFc[l] + o*K + T*256 + sub;
    float2 w[16];
    #pragma unroll
    for(int kk=0;kk<16;kk++) w[kk]=Wrow[kk<<4];
    float2* pp = g_part + PBASEc[l] + b*PSTRc[l] + T*(16*nm) + o*nm;
    const float2* shs = sh + sub;
    for(int m=0;m<nm;m++){
        float ar=0.f, ai=0.f;
        #pragma unroll
        for(int kk=0;kk<16;kk++){
            const float2 x=shs[m*256+(kk<<4)];
            ar = fmaf(w[kk].x,x.x, fmaf(-w[kk].y,x.y, ar));
            ai = fmaf(w[kk].x,x.y, fmaf( w[kk].y,x.x, ai));
        }
        #pragma unroll
        for(int s=1;s<16;s<<=1){
            ar += __shfl_xor(ar,s,64);
            ai += __shfl_xor(ai,s,64);
        }
        if(sub==0) pp[m]=make_float2(ar,ai);
    }
}

// ------- kernel 4: reduce partials over tiles -> out --------------------------
// grid (256 b) x 448; thread r<400 handles out[b*400 + r].
__global__ void __launch_bounds__(448) k_red(float2* __restrict__ out){
    const int b=blockIdx.x, r=threadIdx.x;
    if(r>=400) return;
    const int l = (r<16)?0:(r<64)?1:(r<144)?2:(r<256)?3:4;
    const int om = r - ROFFc[l];            // == o*NM + m by row ordering
    const int nm=NMc[l], nt=NTc[l];
    const float2* pp = g_part + PBASEc[l] + b*PSTRc[l] + om;
    float2 s = make_float2(0.f,0.f);
    for(int T=0;T<nt;T++){
        float2 v = pp[T*16*nm];
        s.x += v.x; s.y += v.y;
    }
    out[b*400 + r] = s;
}

// ---------------- host-side CG table (identical every call; graph-safe) -------
static double h_fact(int n){ double r=1.0; for(int i=2;i<=n;i++) r*=(double)i; return r; }

static double h_cg_coef(int j1,int m1,int j2,int m2,int j,int m){
    if(m1+m2!=m) return 0.0;
    double pref = sqrt((2.0*j+1.0)*h_fact(j+j1-j2)*h_fact(j-j1+j2)*h_fact(j1+j2-j)/h_fact(j1+j2+j+1));
    pref *= sqrt(h_fact(j+m)*h_fact(j-m)*h_fact(j1-m1)*h_fact(j1+m1)*h_fact(j2-m2)*h_fact(j2+m2));
    double s=0.0;
    for(int k=0;k<=j1+j2-j;k++){
        int a=j1-m1-k, bb=j2+m2-k, c=j-j2+m1+k, dd=j-j1-m2+k;
        if(a<0||bb<0||c<0||dd<0) continue;
        double term = 1.0/(h_fact(k)*h_fact(j1+j2-j-k)*h_fact(a)*h_fact(bb)*h_fact(c)*h_fact(dd));
        s += (k&1)? -term : term;
    }
    return pref*s;
}

static const int HT_L [NTRI]={0,0,0,0,0, 1,1,1,1,1,1,1,1, 2,2,2,2,2,2,2,2,2,2, 3,3,3,3,3,3,3,3,3,3, 4,4,4,4,4,4,4,4,4};
static const int HT_L1[NTRI]={0,1,2,3,4, 1,1,2,2,3,3,4,4, 1,2,2,2,3,3,3,4,4,4, 2,2,3,3,3,3,4,4,4,4, 2,3,3,3,4,4,4,4,4};
static const int HT_L2[NTRI]={0,1,2,3,4, 0,1,1,2,2,3,3,4, 1,0,1,2,1,2,3,2,3,4, 1,2,0,1,2,3,1,2,3,4, 2,1,2,3,0,1,2,3,4};

static float h_cgtab[NTRI][81];

static void build_cg_host(){
    for(int tr=0;tr<NTRI;tr++){
        const int l=HT_L[tr], l1=HT_L1[tr], l2=HT_L2[tr];
        const int nm=2*l+1, n1=2*l1+1;
        for(int s=0;s<81;s++) h_cgtab[tr][s]=0.f;
        for(int mi=0;mi<nm;mi++)
            for(int p=0;p<n1;p++){
                const int m=mi-l, m1=p-l1, m2=m-m1;
                if(m2>=-l2 && m2<=l2)
                    h_cgtab[tr][mi*n1+p]=(float)h_cg_coef(l1,m1,l2,m2,l,m);
            }
    }
}

// ---------------- launcher ----------------
extern "C" void kernel_launch(void* const* d_in, const int* in_sizes, int n_in,
                              void* d_out, int out_size, void* d_ws, size_t ws_size,
                              hipStream_t stream){
    const float2* Fs = (const float2*)d_in[0];   // [256,400,2] fp32
    const float2* W  = (const float2*)d_in[1];   // [172032,2]  fp32
    float2* out = (float2*)d_out;                // [256,400,2] fp32

    build_cg_host();                             // same values every call
    void* dcg=nullptr;
    hipGetSymbolAddress(&dcg, HIP_SYMBOL(g_cgcD));
    hipMemcpyAsync(dcg, h_cgtab, sizeof(h_cgtab), hipMemcpyHostToDevice, stream);

    k_var<<<dim3(NTRI,32),256,0,stream>>>(Fs);
    k_inv<<<dim3(NTRI),256,0,stream>>>();
    k_mm <<<dim3(NTRI,B_SZ),256,0,stream>>>(Fs,W);
    k_red<<<dim3(B_SZ),448,0,stream>>>(out);
}